// Round 5
// baseline (1662.806 us; speedup 1.0000x reference)
//
#include <hip/hip_runtime.h>
#include <hip/hip_fp16.h>

// AnyPrecisionLinear (4-bit bitplane LUT dequant + GEMM), MI355X gfx950.
// HARNESS DTYPE MAPPING (per header: "bfloat16 -> __hip_bfloat16*, else
// float*"): the reference's fp16 tensors are staged as FLOAT32 on device.
// So x, lut, bias are const float*, output Y is float*. The f32 values are
// exactly fp16-representable -> convert to fp16 losslessly and use f16 MFMA.
// Evidence: R2 absmax = bf16view(fp16-clamp bits); R3/4 absmax = saturated
// clamp signature under bf16 reads; out npz 158MB ~ compressed 268MB f32.

using f16x8 = __attribute__((ext_vector_type(8))) _Float16;
using f32x4 = __attribute__((ext_vector_type(4))) float;

#define IN_F   4096
#define OUT_F  4096
#define M_ROWS 16384
#define PLANE_STRIDE (OUT_F * (IN_F / 32))  // 524288 words per bitplane
#define CLAMP_V 65176.484375f               // fp16max * (1 - 0.005)

union h8 {
  _Float16 h[8];
  uint4 v;
};

// ---------------------------------------------------------------- dequant ---
// qw bitplanes + lut(f32, fp16-valued) -> W (fp16) in d_ws.
// 2 output channels per 256-thread block; thread = one 32-bit word group.
__global__ __launch_bounds__(256) void dequant_kernel(
    const int* __restrict__ qw, const float* __restrict__ lut,
    _Float16* __restrict__ W) {
  __shared__ _Float16 luts[32];  // 2 LUT rows of 16
  const int t = threadIdx.x;
  if (t < 32) luts[t] = (_Float16)lut[blockIdx.x * 32 + t];
  __syncthreads();

  const int o = (blockIdx.x << 1) + (t >> 7);  // output channel
  const int g = t & 127;                       // word index within row
  const int base = o * (IN_F / 32) + g;

  const unsigned w0 = (unsigned)qw[base];                     // bit 3 (MSB)
  const unsigned w1 = (unsigned)qw[base + PLANE_STRIDE];      // bit 2
  const unsigned w2 = (unsigned)qw[base + 2 * PLANE_STRIDE];  // bit 1
  const unsigned w3 = (unsigned)qw[base + 3 * PLANE_STRIDE];  // bit 0 (LSB)
  const int lo = (t >> 7) << 4;

  h8 out[4];
#pragma unroll
  for (int b = 0; b < 32; ++b) {
    unsigned code = (((w0 >> b) & 1u) << 3) | (((w1 >> b) & 1u) << 2) |
                    (((w2 >> b) & 1u) << 1) | ((w3 >> b) & 1u);
    out[b >> 3].h[b & 7] = luts[lo + code];
  }

  uint4* dst = (uint4*)&W[(size_t)o * IN_F + g * 32];
#pragma unroll
  for (int i = 0; i < 4; ++i) dst[i] = out[i].v;
}

// ---------------------------------------------------------------- helpers ---
__device__ __forceinline__ void tile_indices(int bid, int& mt, int& nt) {
  // grid = 4096 (divisible by 8) -> bijective XCD swizzle, mt fastest.
  const int swz = (bid & 7) * 512 + (bid >> 3);
  mt = swz & 127;
  nt = swz >> 7;
}

// ------------------------------------------------------------ GEMM (ws W) ---
// 128x128 tile, BK=32, 256 threads = 4 waves (2x2), wave owns 64x64 =
// 4x4 fragments of mfma_f32_16x16x32_f16. A staged f32->fp16 cvt; B staged
// fp16 direct from ws. One LDS buffer, 2-barrier K-loop.
__global__ __launch_bounds__(256) void gemm_ws(
    const float* __restrict__ X, const _Float16* __restrict__ W,
    const float* __restrict__ bias, float* __restrict__ Y) {
  __shared__ _Float16 As[128 * 32];  // 8 KiB each
  __shared__ _Float16 Bs[128 * 32];

  const int t = threadIdx.x;
  const int lane = t & 63;
  const int wv = t >> 6;
  const int wm = wv >> 1;
  const int wn = wv & 1;

  int mt, nt;
  tile_indices(blockIdx.x, mt, nt);

  // Staging map: 2 threads per row; each covers 16 k-values.
  const int srow = t >> 1;
  const int hb = (t & 1) * 16;
  const size_t ax = (size_t)(mt * 128 + srow) * IN_F + hb;
  const size_t bx = (size_t)(nt * 128 + srow) * IN_F + hb;

  f32x4 acc[4][4] = {};
  const int frow = lane & 15;
  const int koff = (lane >> 4) * 8;

  for (int kt = 0; kt < IN_F / 32; ++kt) {
    const int k0 = kt * 32;
    // A: 4x float4 loads -> 16 fp16 -> 2x 16B LDS writes.
    h8 a0, a1;
#pragma unroll
    for (int c = 0; c < 2; ++c) {
      const float4 v0 = *(const float4*)&X[ax + k0 + c * 8];
      const float4 v1 = *(const float4*)&X[ax + k0 + c * 8 + 4];
      a0.h[c * 4 + 0] = (_Float16)v0.x; a0.h[c * 4 + 1] = (_Float16)v0.y;
      a0.h[c * 4 + 2] = (_Float16)v0.z; a0.h[c * 4 + 3] = (_Float16)v0.w;
      (void)v1;
      a1.h[c * 4 + 0] = (_Float16)v1.x; a1.h[c * 4 + 1] = (_Float16)v1.y;
      a1.h[c * 4 + 2] = (_Float16)v1.z; a1.h[c * 4 + 3] = (_Float16)v1.w;
    }
    // interleave fix: a0 holds k {0,1,2,3, 8,9,10,11}? No — rebuild linearly:
    h8 w0, w1;
    w0.h[0] = a0.h[0]; w0.h[1] = a0.h[1]; w0.h[2] = a0.h[2]; w0.h[3] = a0.h[3];
    w0.h[4] = a1.h[0]; w0.h[5] = a1.h[1]; w0.h[6] = a1.h[2]; w0.h[7] = a1.h[3];
    w1.h[0] = a0.h[4]; w1.h[1] = a0.h[5]; w1.h[2] = a0.h[6]; w1.h[3] = a0.h[7];
    w1.h[4] = a1.h[4]; w1.h[5] = a1.h[5]; w1.h[6] = a1.h[6]; w1.h[7] = a1.h[7];
    *(uint4*)&As[srow * 32 + hb] = w0.v;
    *(uint4*)&As[srow * 32 + hb + 8] = w1.v;
    // B: fp16 direct, 2x 16B.
    *(uint4*)&Bs[srow * 32 + hb] = *(const uint4*)&W[bx + k0];
    *(uint4*)&Bs[srow * 32 + hb + 8] = *(const uint4*)&W[bx + k0 + 8];
    __syncthreads();

    f16x8 af[4], bf[4];
#pragma unroll
    for (int i = 0; i < 4; ++i) {
      af[i] = *(const f16x8*)&As[(wm * 64 + i * 16 + frow) * 32 + koff];
      bf[i] = *(const f16x8*)&Bs[(wn * 64 + i * 16 + frow) * 32 + koff];
    }
#pragma unroll
    for (int i = 0; i < 4; ++i)
#pragma unroll
      for (int j = 0; j < 4; ++j)
        acc[i][j] = __builtin_amdgcn_mfma_f32_16x16x32_f16(af[i], bf[j],
                                                           acc[i][j], 0, 0, 0);
    __syncthreads();
  }

  // Epilogue. C/D mapping (m89): col = lane&15, row = (lane>>4)*4 + reg.
  const int col_base = nt * 128 + wn * 64 + (lane & 15);
  const int row_base = mt * 128 + wm * 64 + (lane >> 4) * 4;
#pragma unroll
  for (int j = 0; j < 4; ++j) {
    const int col = col_base + j * 16;
    const float bv = bias[col];
#pragma unroll
    for (int i = 0; i < 4; ++i) {
      const int row = row_base + i * 16;
#pragma unroll
      for (int r = 0; r < 4; ++r) {
        float v = acc[i][j][r] + bv;
        v = fminf(fmaxf(v, -CLAMP_V), CLAMP_V);
        Y[(size_t)(row + r) * OUT_F + col] = v;
      }
    }
  }
}

// ------------------------------------------------- fused fallback (no ws) ---
__global__ __launch_bounds__(256) void gemm_fused(
    const float* __restrict__ X, const int* __restrict__ qw,
    const float* __restrict__ lut, const float* __restrict__ bias,
    float* __restrict__ Y) {
  __shared__ _Float16 As[128 * 32];
  __shared__ _Float16 Bs[128 * 32];
  __shared__ _Float16 lutS[128 * 16];

  const int t = threadIdx.x;
  const int lane = t & 63;
  const int wv = t >> 6;
  const int wm = wv >> 1;
  const int wn = wv & 1;

  int mt, nt;
  tile_indices(blockIdx.x, mt, nt);

  // Preload this block's 128 LUT rows (2048 halves; 8 per thread, cvt f32).
  {
    h8 lv;
#pragma unroll
    for (int c = 0; c < 8; ++c)
      lv.h[c] = (_Float16)lut[(size_t)(nt * 128) * 16 + t * 8 + c];
    *(uint4*)&lutS[t * 8] = lv.v;
  }

  const int srow = t >> 1;
  const int hb = (t & 1) * 16;
  const size_t ax = (size_t)(mt * 128 + srow) * IN_F + hb;
  const int qb = (nt * 128 + srow) * (IN_F / 32);

  f32x4 acc[4][4] = {};
  const int frow = lane & 15;
  const int koff = (lane >> 4) * 8;

  __syncthreads();  // lutS ready

  for (int kt = 0; kt < IN_F / 32; ++kt) {
    const int k0 = kt * 32;
    // A staging with cvt.
    h8 w0, w1;
    {
      const float4 v0 = *(const float4*)&X[ax + k0];
      const float4 v1 = *(const float4*)&X[ax + k0 + 4];
      const float4 v2 = *(const float4*)&X[ax + k0 + 8];
      const float4 v3 = *(const float4*)&X[ax + k0 + 12];
      w0.h[0] = (_Float16)v0.x; w0.h[1] = (_Float16)v0.y;
      w0.h[2] = (_Float16)v0.z; w0.h[3] = (_Float16)v0.w;
      w0.h[4] = (_Float16)v1.x; w0.h[5] = (_Float16)v1.y;
      w0.h[6] = (_Float16)v1.z; w0.h[7] = (_Float16)v1.w;
      w1.h[0] = (_Float16)v2.x; w1.h[1] = (_Float16)v2.y;
      w1.h[2] = (_Float16)v2.z; w1.h[3] = (_Float16)v2.w;
      w1.h[4] = (_Float16)v3.x; w1.h[5] = (_Float16)v3.y;
      w1.h[6] = (_Float16)v3.z; w1.h[7] = (_Float16)v3.w;
    }
    *(uint4*)&As[srow * 32 + hb] = w0.v;
    *(uint4*)&As[srow * 32 + hb + 8] = w1.v;
    // B dequant: this thread covers bits hb..hb+15 of word kt for row srow.
    {
      const int base = qb + kt;
      const unsigned q0 = (unsigned)qw[base];
      const unsigned q1 = (unsigned)qw[base + PLANE_STRIDE];
      const unsigned q2 = (unsigned)qw[base + 2 * PLANE_STRIDE];
      const unsigned q3 = (unsigned)qw[base + 3 * PLANE_STRIDE];
      const _Float16* lr = &lutS[srow * 16];
      h8 t0, t1;
#pragma unroll
      for (int b2 = 0; b2 < 16; ++b2) {
        const int b = hb + b2;
        unsigned code = (((q0 >> b) & 1u) << 3) | (((q1 >> b) & 1u) << 2) |
                        (((q2 >> b) & 1u) << 1) | ((q3 >> b) & 1u);
        if (b2 < 8) t0.h[b2] = lr[code];
        else t1.h[b2 - 8] = lr[code];
      }
      *(uint4*)&Bs[srow * 32 + hb] = t0.v;
      *(uint4*)&Bs[srow * 32 + hb + 8] = t1.v;
    }
    __syncthreads();

    f16x8 af[4], bf[4];
#pragma unroll
    for (int i = 0; i < 4; ++i) {
      af[i] = *(const f16x8*)&As[(wm * 64 + i * 16 + frow) * 32 + koff];
      bf[i] = *(const f16x8*)&Bs[(wn * 64 + i * 16 + frow) * 32 + koff];
    }
#pragma unroll
    for (int i = 0; i < 4; ++i)
#pragma unroll
      for (int j = 0; j < 4; ++j)
        acc[i][j] = __builtin_amdgcn_mfma_f32_16x16x32_f16(af[i], bf[j],
                                                           acc[i][j], 0, 0, 0);
    __syncthreads();
  }

  const int col_base = nt * 128 + wn * 64 + (lane & 15);
  const int row_base = mt * 128 + wm * 64 + (lane >> 4) * 4;
#pragma unroll
  for (int j = 0; j < 4; ++j) {
    const int col = col_base + j * 16;
    const float bv = bias[col];
#pragma unroll
    for (int i = 0; i < 4; ++i) {
      const int row = row_base + i * 16;
#pragma unroll
      for (int r = 0; r < 4; ++r) {
        float v = acc[i][j][r] + bv;
        v = fminf(fmaxf(v, -CLAMP_V), CLAMP_V);
        Y[(size_t)(row + r) * OUT_F + col] = v;
      }
    }
  }
}

// ----------------------------------------------------------------- launch ---
extern "C" void kernel_launch(void* const* d_in, const int* in_sizes, int n_in,
                              void* d_out, int out_size, void* d_ws,
                              size_t ws_size, hipStream_t stream) {
  const float* X = (const float*)d_in[0];     // fp16-valued f32
  const int* qw = (const int*)d_in[1];
  const float* lut = (const float*)d_in[2];   // fp16-valued f32
  const float* bias = (const float*)d_in[3];  // fp16-valued f32
  float* Y = (float*)d_out;

  const size_t w_bytes = (size_t)OUT_F * IN_F * sizeof(_Float16);  // 32 MiB
  const int grid = (M_ROWS / 128) * (OUT_F / 128);                 // 4096

  if (ws_size >= w_bytes && d_ws != nullptr) {
    _Float16* W16 = (_Float16*)d_ws;
    dequant_kernel<<<OUT_F / 2, 256, 0, stream>>>(qw, lut, W16);
    gemm_ws<<<grid, 256, 0, stream>>>(X, W16, bias, Y);
  } else {
    gemm_fused<<<grid, 256, 0, stream>>>(X, qw, lut, bias, Y);
  }
}

// Round 8
// 1363.620 us; speedup vs baseline: 1.2194x; 1.2194x over previous
//
#include <hip/hip_runtime.h>
#include <hip/hip_fp16.h>

// AnyPrecisionLinear (4-bit bitplane LUT dequant + GEMM), MI355X gfx950.
// fp16 tensors are staged as FLOAT32 on device (harness maps fp16 -> float*).
// R5 counters: FETCH=4.33GB from mt-fastest swizzle (A re-fetch), MfmaUtil 17%.
// R6/R7: 3-dispatch variant died in container twice (infra-suspected); this
// round de-risks back to the R5-proven 2-dispatch shape with the two fixes:
// nt-fastest swizzle + gl_lds for B. A stays reg-staged f32->fp16 (R5 path).

using f16x8 = __attribute__((ext_vector_type(8))) _Float16;
using f32x4 = __attribute__((ext_vector_type(4))) float;

#define IN_F   4096
#define OUT_F  4096
#define M_ROWS 16384
#define PLANE_STRIDE (OUT_F * (IN_F / 32))  // 524288 words per bitplane
#define CLAMP_V 65176.484375f               // fp16max * (1 - 0.005)

union h8 {
  _Float16 h[8];
  uint4 v;
};

// ---------------------------------------------------------------- dequant ---
// qw bitplanes + lut(f32, fp16-valued) -> W (fp16) in d_ws.
__global__ __launch_bounds__(256) void dequant_kernel(
    const int* __restrict__ qw, const float* __restrict__ lut,
    _Float16* __restrict__ W) {
  __shared__ _Float16 luts[32];
  const int t = threadIdx.x;
  if (t < 32) luts[t] = (_Float16)lut[blockIdx.x * 32 + t];
  __syncthreads();

  const int o = (blockIdx.x << 1) + (t >> 7);
  const int g = t & 127;
  const int base = o * (IN_F / 32) + g;

  const unsigned w0 = (unsigned)qw[base];                     // bit 3 (MSB)
  const unsigned w1 = (unsigned)qw[base + PLANE_STRIDE];      // bit 2
  const unsigned w2 = (unsigned)qw[base + 2 * PLANE_STRIDE];  // bit 1
  const unsigned w3 = (unsigned)qw[base + 3 * PLANE_STRIDE];  // bit 0 (LSB)
  const int lo = (t >> 7) << 4;

  h8 out[4];
#pragma unroll
  for (int b = 0; b < 32; ++b) {
    unsigned code = (((w0 >> b) & 1u) << 3) | (((w1 >> b) & 1u) << 2) |
                    (((w2 >> b) & 1u) << 1) | ((w3 >> b) & 1u);
    out[b >> 3].h[b & 7] = luts[lo + code];
  }

  uint4* dst = (uint4*)&W[(size_t)o * IN_F + g * 32];
#pragma unroll
  for (int i = 0; i < 4; ++i) dst[i] = out[i].v;
}

// ---------------------------------------------------------------- helpers ---
__device__ __forceinline__ void gl_lds16(const void* g, void* l) {
  __builtin_amdgcn_global_load_lds(
      (const __attribute__((address_space(1))) void*)g,
      (__attribute__((address_space(3))) void*)l, 16, 0, 0);
}

__device__ __forceinline__ void tile_indices(int bid, int& mt, int& nt) {
  // nt-fastest within each XCD chunk: chunk = 16 mt x 32 nt. A-panel (2 MB
  // f32) is read ~once then L2-resident across its 32 nt; W lives in L2/L3.
  const int swz = (bid & 7) * 512 + (bid >> 3);
  nt = swz & 31;
  mt = swz >> 5;
}

// --------------------------------------- GEMM: A f32 reg-cvt, B gl_lds ws ---
// 128x128 tile, BK=32, 4 waves (2x2), 4x4 fragments of mfma_f32_16x16x32_f16.
__global__ __launch_bounds__(256) void gemm_ws(
    const float* __restrict__ X, const _Float16* __restrict__ W,
    const float* __restrict__ bias, float* __restrict__ Y) {
  __shared__ _Float16 As[128 * 32];  // 8 KiB each, row-major, 64 B rows
  __shared__ _Float16 Bs[128 * 32];

  const int t = threadIdx.x;
  const int lane = t & 63;
  const int wv = t >> 6;
  const int wm = wv >> 1;
  const int wn = wv & 1;

  int mt, nt;
  tile_indices(blockIdx.x, mt, nt);

  // A staging (reg-cvt): 2 threads per row, 16 halves each.
  const int srow = t >> 1;
  const int hb = (t & 1) * 16;
  const size_t ax = (size_t)(mt * 128 + srow) * IN_F + hb;

  // B staging (gl_lds, linear): thread t covers halves t*8 (call0) /
  // t*8+2048 (call1); row = t>>2 (+64), k-offset = (t&3)*8.
  const int r0 = t >> 2;
  const int q0 = (t & 3) * 8;
  const size_t b_off0 = (size_t)(nt * 128 + r0) * IN_F + q0;
  const size_t b_off1 = (size_t)(nt * 128 + r0 + 64) * IN_F + q0;
  _Float16* Bs_d = &Bs[wv * 512];  // wave-uniform dest (HW: base + lane*16B)

  f32x4 acc[4][4] = {};
  const int frow = lane & 15;
  const int koff = (lane >> 4) * 8;

  for (int kt = 0; kt < IN_F / 32; ++kt) {
    const int k0 = kt * 32;
    // B: async global->LDS (fp16, no conversion needed).
    gl_lds16(&W[b_off0 + k0], Bs_d);
    gl_lds16(&W[b_off1 + k0], Bs_d + 2048);
    // A: f32 loads -> cvt -> LDS (16 halves/thread).
    h8 w0, w1;
    {
      const float4 v0 = *(const float4*)&X[ax + k0];
      const float4 v1 = *(const float4*)&X[ax + k0 + 4];
      const float4 v2 = *(const float4*)&X[ax + k0 + 8];
      const float4 v3 = *(const float4*)&X[ax + k0 + 12];
      w0.h[0] = (_Float16)v0.x; w0.h[1] = (_Float16)v0.y;
      w0.h[2] = (_Float16)v0.z; w0.h[3] = (_Float16)v0.w;
      w0.h[4] = (_Float16)v1.x; w0.h[5] = (_Float16)v1.y;
      w0.h[6] = (_Float16)v1.z; w0.h[7] = (_Float16)v1.w;
      w1.h[0] = (_Float16)v2.x; w1.h[1] = (_Float16)v2.y;
      w1.h[2] = (_Float16)v2.z; w1.h[3] = (_Float16)v2.w;
      w1.h[4] = (_Float16)v3.x; w1.h[5] = (_Float16)v3.y;
      w1.h[6] = (_Float16)v3.z; w1.h[7] = (_Float16)v3.w;
    }
    *(uint4*)&As[srow * 32 + hb] = w0.v;
    *(uint4*)&As[srow * 32 + hb + 8] = w1.v;
    __syncthreads();  // drains vmcnt (gl_lds) + lgkmcnt (ds_write)

    f16x8 af[4], bf[4];
#pragma unroll
    for (int i = 0; i < 4; ++i) {
      af[i] = *(const f16x8*)&As[(wm * 64 + i * 16 + frow) * 32 + koff];
      bf[i] = *(const f16x8*)&Bs[(wn * 64 + i * 16 + frow) * 32 + koff];
    }
#pragma unroll
    for (int i = 0; i < 4; ++i)
#pragma unroll
      for (int j = 0; j < 4; ++j)
        acc[i][j] = __builtin_amdgcn_mfma_f32_16x16x32_f16(af[i], bf[j],
                                                           acc[i][j], 0, 0, 0);
    __syncthreads();
  }

  // Epilogue. C/D mapping (m89): col = lane&15, row = (lane>>4)*4 + reg.
  const int col_base = nt * 128 + wn * 64 + (lane & 15);
  const int row_base = mt * 128 + wm * 64 + (lane >> 4) * 4;
#pragma unroll
  for (int j = 0; j < 4; ++j) {
    const int col = col_base + j * 16;
    const float bv = bias[col];
#pragma unroll
    for (int i = 0; i < 4; ++i) {
      const int row = row_base + i * 16;
#pragma unroll
      for (int r = 0; r < 4; ++r) {
        float v = acc[i][j][r] + bv;
        v = fminf(fmaxf(v, -CLAMP_V), CLAMP_V);
        Y[(size_t)(row + r) * OUT_F + col] = v;
      }
    }
  }
}

// ------------------------------------------------- fused fallback (no ws) ---
__global__ __launch_bounds__(256) void gemm_fused(
    const float* __restrict__ X, const int* __restrict__ qw,
    const float* __restrict__ lut, const float* __restrict__ bias,
    float* __restrict__ Y) {
  __shared__ _Float16 As[128 * 32];
  __shared__ _Float16 Bs[128 * 32];
  __shared__ _Float16 lutS[128 * 16];

  const int t = threadIdx.x;
  const int lane = t & 63;
  const int wv = t >> 6;
  const int wm = wv >> 1;
  const int wn = wv & 1;

  int mt, nt;
  tile_indices(blockIdx.x, mt, nt);

  {
    h8 lv;
#pragma unroll
    for (int c = 0; c < 8; ++c)
      lv.h[c] = (_Float16)lut[(size_t)(nt * 128) * 16 + t * 8 + c];
    *(uint4*)&lutS[t * 8] = lv.v;
  }

  const int srow = t >> 1;
  const int hb = (t & 1) * 16;
  const size_t ax = (size_t)(mt * 128 + srow) * IN_F + hb;
  const int qb = (nt * 128 + srow) * (IN_F / 32);

  f32x4 acc[4][4] = {};
  const int frow = lane & 15;
  const int koff = (lane >> 4) * 8;

  __syncthreads();

  for (int kt = 0; kt < IN_F / 32; ++kt) {
    const int k0 = kt * 32;
    h8 w0, w1;
    {
      const float4 v0 = *(const float4*)&X[ax + k0];
      const float4 v1 = *(const float4*)&X[ax + k0 + 4];
      const float4 v2 = *(const float4*)&X[ax + k0 + 8];
      const float4 v3 = *(const float4*)&X[ax + k0 + 12];
      w0.h[0] = (_Float16)v0.x; w0.h[1] = (_Float16)v0.y;
      w0.h[2] = (_Float16)v0.z; w0.h[3] = (_Float16)v0.w;
      w0.h[4] = (_Float16)v1.x; w0.h[5] = (_Float16)v1.y;
      w0.h[6] = (_Float16)v1.z; w0.h[7] = (_Float16)v1.w;
      w1.h[0] = (_Float16)v2.x; w1.h[1] = (_Float16)v2.y;
      w1.h[2] = (_Float16)v2.z; w1.h[3] = (_Float16)v2.w;
      w1.h[4] = (_Float16)v3.x; w1.h[5] = (_Float16)v3.y;
      w1.h[6] = (_Float16)v3.z; w1.h[7] = (_Float16)v3.w;
    }
    *(uint4*)&As[srow * 32 + hb] = w0.v;
    *(uint4*)&As[srow * 32 + hb + 8] = w1.v;
    {
      const int base = qb + kt;
      const unsigned q0 = (unsigned)qw[base];
      const unsigned q1 = (unsigned)qw[base + PLANE_STRIDE];
      const unsigned q2 = (unsigned)qw[base + 2 * PLANE_STRIDE];
      const unsigned q3 = (unsigned)qw[base + 3 * PLANE_STRIDE];
      const _Float16* lr = &lutS[srow * 16];
      h8 t0, t1;
#pragma unroll
      for (int b2 = 0; b2 < 16; ++b2) {
        const int b = hb + b2;
        unsigned code = (((q0 >> b) & 1u) << 3) | (((q1 >> b) & 1u) << 2) |
                        (((q2 >> b) & 1u) << 1) | ((q3 >> b) & 1u);
        if (b2 < 8) t0.h[b2] = lr[code];
        else t1.h[b2 - 8] = lr[code];
      }
      *(uint4*)&Bs[srow * 32 + hb] = t0.v;
      *(uint4*)&Bs[srow * 32 + hb + 8] = t1.v;
    }
    __syncthreads();

    f16x8 af[4], bf[4];
#pragma unroll
    for (int i = 0; i < 4; ++i) {
      af[i] = *(const f16x8*)&As[(wm * 64 + i * 16 + frow) * 32 + koff];
      bf[i] = *(const f16x8*)&Bs[(wn * 64 + i * 16 + frow) * 32 + koff];
    }
#pragma unroll
    for (int i = 0; i < 4; ++i)
#pragma unroll
      for (int j = 0; j < 4; ++j)
        acc[i][j] = __builtin_amdgcn_mfma_f32_16x16x32_f16(af[i], bf[j],
                                                           acc[i][j], 0, 0, 0);
    __syncthreads();
  }

  const int col_base = nt * 128 + wn * 64 + (lane & 15);
  const int row_base = mt * 128 + wm * 64 + (lane >> 4) * 4;
#pragma unroll
  for (int j = 0; j < 4; ++j) {
    const int col = col_base + j * 16;
    const float bv = bias[col];
#pragma unroll
    for (int i = 0; i < 4; ++i) {
      const int row = row_base + i * 16;
#pragma unroll
      for (int r = 0; r < 4; ++r) {
        float v = acc[i][j][r] + bv;
        v = fminf(fmaxf(v, -CLAMP_V), CLAMP_V);
        Y[(size_t)(row + r) * OUT_F + col] = v;
      }
    }
  }
}

// ----------------------------------------------------------------- launch ---
extern "C" void kernel_launch(void* const* d_in, const int* in_sizes, int n_in,
                              void* d_out, int out_size, void* d_ws,
                              size_t ws_size, hipStream_t stream) {
  const float* X = (const float*)d_in[0];     // fp16-valued f32
  const int* qw = (const int*)d_in[1];
  const float* lut = (const float*)d_in[2];   // fp16-valued f32
  const float* bias = (const float*)d_in[3];  // fp16-valued f32
  float* Y = (float*)d_out;

  const size_t w_bytes = (size_t)OUT_F * IN_F * sizeof(_Float16);  // 32 MiB
  const int grid = (M_ROWS / 128) * (OUT_F / 128);                 // 4096

  if (ws_size >= w_bytes && d_ws != nullptr) {
    _Float16* W16 = (_Float16*)d_ws;
    dequant_kernel<<<OUT_F / 2, 256, 0, stream>>>(qw, lut, W16);
    gemm_ws<<<grid, 256, 0, stream>>>(X, W16, bias, Y);
  } else {
    gemm_fused<<<grid, 256, 0, stream>>>(X, qw, lut, bias, Y);
  }
}